// Round 1
// 897.573 us; speedup vs baseline: 1.0133x; 1.0133x over previous
//
#include <hip/hip_runtime.h>

#define T_STEPS 512
#define HS 20       // hidden size
#define F0 10       // input features (layer 0)
#define BPB 6       // batches per block: lane-group g handles batches {g, g+3}
#define NB_TOT 4096
#define NBLK ((NB_TOT + BPB - 1) / BPB)   // 683
#define CHK 32                            // chunk length (steps per barrier)
#define NCH (T_STEPS / CHK)               // 16 chunks

__device__ __forceinline__ float sigmoid_fast(float v) {
    return __fdividef(1.f, 1.f + __expf(-v));
}
__device__ __forceinline__ float tanh_fast(float v) {
    return 1.f - __fdividef(2.f, __expf(2.f * v) + 1.f);
}
#define PIN(v) asm volatile("" : "+v"(v))

// Chunk-staggered producer/consumer:
//   wave0 produces layer0 h0 for chunk k into buf[k&1] (also its own h-broadcast
//   medium); wave1 consumes chunk k-1 from buf[(k-1)&1]. ONE __syncthreads per
//   chunk (18 total vs 513). x(t+1) is prefetched during step t and folded into
//   bias-initialized accumulators at the top of step t+1, so global-load latency
//   never sits inside the serial FMA chain.
//   LDS 31.2 KB/block -> 5 blocks/CU possible; 683 blocks (2.67/CU) co-resident.
__global__ __launch_bounds__(128, 2)
void lstm2_fc_kernel(const float* __restrict__ x,
                     const float* __restrict__ wih0, const float* __restrict__ whh0,
                     const float* __restrict__ bih0, const float* __restrict__ bhh0,
                     const float* __restrict__ wih1, const float* __restrict__ whh1,
                     const float* __restrict__ bih1, const float* __restrict__ bhh1,
                     const float* __restrict__ wfc,  const float* __restrict__ bfc,
                     float* __restrict__ out)
{
    const int tid  = threadIdx.x;
    const int wid  = tid >> 6;
    const int lane = tid & 63;
    const int g    = (lane / HS) % 3;   // lanes 60..63 shadow group 0 (benign dups)
    const int u    = lane % HS;
    const int bgA  = blockIdx.x * BPB + g;          // < 4096 always (682*6+2=4094)
    const int bgBr = blockIdx.x * BPB + g + 3;
    const bool okB = (bgBr < NB_TOT);
    const int bgB  = okB ? bgBr : (NB_TOT - 1);     // clamp reads

    __shared__ float buf[2][CHK][BPB][HS];  // double-buffered h0 chunks
    __shared__ float s_h1[BPB][HS];         // wave1-private recurrence state

    for (int i = tid; i < BPB * HS; i += 128) {
        (&s_h1[0][0])[i]            = 0.f;
        (&buf[1][CHK - 1][0][0])[i] = 0.f;  // h0(-1) read slot for k=0,s=0
    }

    // ---- per-lane weights, SHARED storage between the two wave roles ----
    // wave0: w[q][0..9] = wih0 row, w[q][10..29] = whh0 row, 30..39 unused
    // wave1: w[q][0..19] = wih1 row, w[q][20..39] = whh1 row
    float w[4][2 * HS], bias[4];
    if (wid == 0) {
        #pragma unroll
        for (int q = 0; q < 4; ++q) {
            const int row = q * HS + u;
            #pragma unroll
            for (int f = 0; f < F0; ++f) { w[q][f] = wih0[row * F0 + f]; PIN(w[q][f]); }
            #pragma unroll
            for (int j = 0; j < HS; ++j) { w[q][F0 + j] = whh0[row * HS + j]; PIN(w[q][F0 + j]); }
            bias[q] = bih0[row] + bhh0[row]; PIN(bias[q]);
        }
    } else {
        #pragma unroll
        for (int q = 0; q < 4; ++q) {
            const int row = q * HS + u;
            #pragma unroll
            for (int j = 0; j < HS; ++j) { w[q][j]      = wih1[row * HS + j]; PIN(w[q][j]); }
            #pragma unroll
            for (int j = 0; j < HS; ++j) { w[q][HS + j] = whh1[row * HS + j]; PIN(w[q][HS + j]); }
            bias[q] = bih1[row] + bhh1[row]; PIN(bias[q]);
        }
    }

    float cA = 0.f, cB = 0.f;            // c0 (wave0) / c1 (wave1) for the 2 batches
    const float* xbA = x + (size_t)bgA * (T_STEPS * F0);
    const float* xbB = x + (size_t)bgB * (T_STEPS * F0);

    // wave0 x-prefetch registers: x(t) loaded one step ahead
    float2 xnA[F0 / 2], xnB[F0 / 2];
    if (wid == 0) {
        const float2* pA = (const float2*)xbA;
        const float2* pB = (const float2*)xbB;
        #pragma unroll
        for (int f2 = 0; f2 < F0 / 2; ++f2) { xnA[f2] = pA[f2]; xnB[f2] = pB[f2]; }
    }

    __syncthreads();

    for (int k = 0; k <= NCH; ++k) {
        if (wid == 0 && k < NCH) {
            float* wb = &buf[k & 1][0][0][0];
            const float* hprev_c = &buf[(k + 1) & 1][CHK - 1][0][0];  // last h0 of prev chunk
            #pragma unroll 1
            for (int s = 0; s < CHK; ++s) {
                const int t = k * CHK + s;
                // fold prefetched x(t) into fresh accumulators (x-part first, like ref)
                float aA0 = bias[0], aA1 = bias[1], aA2 = bias[2], aA3 = bias[3];
                float aB0 = bias[0], aB1 = bias[1], aB2 = bias[2], aB3 = bias[3];
                #pragma unroll
                for (int f2 = 0; f2 < F0 / 2; ++f2) {
                    const int f = 2 * f2;
                    const float2 vA = xnA[f2], vB = xnB[f2];
                    aA0 = fmaf(vA.x, w[0][f], aA0); aA0 = fmaf(vA.y, w[0][f + 1], aA0);
                    aA1 = fmaf(vA.x, w[1][f], aA1); aA1 = fmaf(vA.y, w[1][f + 1], aA1);
                    aA2 = fmaf(vA.x, w[2][f], aA2); aA2 = fmaf(vA.y, w[2][f + 1], aA2);
                    aA3 = fmaf(vA.x, w[3][f], aA3); aA3 = fmaf(vA.y, w[3][f + 1], aA3);
                    aB0 = fmaf(vB.x, w[0][f], aB0); aB0 = fmaf(vB.y, w[0][f + 1], aB0);
                    aB1 = fmaf(vB.x, w[1][f], aB1); aB1 = fmaf(vB.y, w[1][f + 1], aB1);
                    aB2 = fmaf(vB.x, w[2][f], aB2); aB2 = fmaf(vB.y, w[2][f + 1], aB2);
                    aB3 = fmaf(vB.x, w[3][f], aB3); aB3 = fmaf(vB.y, w[3][f + 1], aB3);
                }
                // issue x(t+1) loads; in flight across the rest of this iteration
                {
                    const int tn = (t + 1 < T_STEPS) ? (t + 1) : (T_STEPS - 1);
                    const float2* pA = (const float2*)(xbA + tn * F0);
                    const float2* pB = (const float2*)(xbB + tn * F0);
                    #pragma unroll
                    for (int f2 = 0; f2 < F0 / 2; ++f2) { xnA[f2] = pA[f2]; xnB[f2] = pB[f2]; }
                }
                // h0(t-1) part; k=0,s=0 reads the pre-zeroed slot
                const float* hb  = (s > 0) ? (wb + (s - 1) * (BPB * HS)) : hprev_c;
                const float* hpA = hb + g * HS;
                const float* hpB = hb + (g + 3) * HS;
                #pragma unroll
                for (int q4 = 0; q4 < HS / 4; ++q4) {
                    const float4 hA = *(const float4*)(hpA + 4 * q4);
                    const float4 hB = *(const float4*)(hpB + 4 * q4);
                    const float eA[4] = {hA.x, hA.y, hA.z, hA.w};
                    const float eB[4] = {hB.x, hB.y, hB.z, hB.w};
                    #pragma unroll
                    for (int e = 0; e < 4; ++e) {
                        const int kk = F0 + 4 * q4 + e;
                        aA0 = fmaf(eA[e], w[0][kk], aA0);  aB0 = fmaf(eB[e], w[0][kk], aB0);
                        aA1 = fmaf(eA[e], w[1][kk], aA1);  aB1 = fmaf(eB[e], w[1][kk], aB1);
                        aA2 = fmaf(eA[e], w[2][kk], aA2);  aB2 = fmaf(eB[e], w[2][kk], aB2);
                        aA3 = fmaf(eA[e], w[3][kk], aA3);  aB3 = fmaf(eB[e], w[3][kk], aB3);
                    }
                }
                const float iA = sigmoid_fast(aA0), fA = sigmoid_fast(aA1);
                const float gA = tanh_fast(aA2),    oA = sigmoid_fast(aA3);
                cA = fA * cA + iA * gA;
                const float hAo = oA * tanh_fast(cA);
                const float iB = sigmoid_fast(aB0), fB = sigmoid_fast(aB1);
                const float gB = tanh_fast(aB2),    oB = sigmoid_fast(aB3);
                cB = fB * cB + iB * gB;
                const float hBo = oB * tanh_fast(cB);
                float* wr = wb + s * (BPB * HS);
                wr[g * HS + u]       = hAo;
                wr[(g + 3) * HS + u] = hBo;
            }
        } else if (wid == 1 && k >= 1) {
            const float* rb = &buf[(k - 1) & 1][0][0][0];
            #pragma unroll 1
            for (int s = 0; s < CHK; ++s) {
                float aA0 = bias[0], aA1 = bias[1], aA2 = bias[2], aA3 = bias[3];
                float aB0 = bias[0], aB1 = bias[1], aB2 = bias[2], aB3 = bias[3];
                const float* hpA = rb + s * (BPB * HS) + g * HS;        // h0(t)
                const float* hpB = rb + s * (BPB * HS) + (g + 3) * HS;
                #pragma unroll
                for (int q4 = 0; q4 < HS / 4; ++q4) {
                    const float4 hA = *(const float4*)(hpA + 4 * q4);
                    const float4 hB = *(const float4*)(hpB + 4 * q4);
                    const float eA[4] = {hA.x, hA.y, hA.z, hA.w};
                    const float eB[4] = {hB.x, hB.y, hB.z, hB.w};
                    #pragma unroll
                    for (int e = 0; e < 4; ++e) {
                        const int kk = 4 * q4 + e;
                        aA0 = fmaf(eA[e], w[0][kk], aA0);  aB0 = fmaf(eB[e], w[0][kk], aB0);
                        aA1 = fmaf(eA[e], w[1][kk], aA1);  aB1 = fmaf(eB[e], w[1][kk], aB1);
                        aA2 = fmaf(eA[e], w[2][kk], aA2);  aB2 = fmaf(eB[e], w[2][kk], aB2);
                        aA3 = fmaf(eA[e], w[3][kk], aA3);  aB3 = fmaf(eB[e], w[3][kk], aB3);
                    }
                }
                const float* ppA = &s_h1[g][0];                        // h1(t-1)
                const float* ppB = &s_h1[g + 3][0];
                #pragma unroll
                for (int q4 = 0; q4 < HS / 4; ++q4) {
                    const float4 hA = *(const float4*)(ppA + 4 * q4);
                    const float4 hB = *(const float4*)(ppB + 4 * q4);
                    const float eA[4] = {hA.x, hA.y, hA.z, hA.w};
                    const float eB[4] = {hB.x, hB.y, hB.z, hB.w};
                    #pragma unroll
                    for (int e = 0; e < 4; ++e) {
                        const int kk = HS + 4 * q4 + e;
                        aA0 = fmaf(eA[e], w[0][kk], aA0);  aB0 = fmaf(eB[e], w[0][kk], aB0);
                        aA1 = fmaf(eA[e], w[1][kk], aA1);  aB1 = fmaf(eB[e], w[1][kk], aB1);
                        aA2 = fmaf(eA[e], w[2][kk], aA2);  aB2 = fmaf(eB[e], w[2][kk], aB2);
                        aA3 = fmaf(eA[e], w[3][kk], aA3);  aB3 = fmaf(eB[e], w[3][kk], aB3);
                    }
                }
                const float iA = sigmoid_fast(aA0), fA = sigmoid_fast(aA1);
                const float gA = tanh_fast(aA2),    oA = sigmoid_fast(aA3);
                const float iB = sigmoid_fast(aB0), fB = sigmoid_fast(aB1);
                const float gB = tanh_fast(aB2),    oB = sigmoid_fast(aB3);
                cA = fA * cA + iA * gA;
                cB = fB * cB + iB * gB;
                __builtin_amdgcn_wave_barrier();   // h1(s-1) reads precede writes
                s_h1[g][u]     = oA * tanh_fast(cA);
                s_h1[g + 3][u] = oB * tanh_fast(cB);
            }
        }
        __syncthreads();   // publish chunk buf[k&1]; WAR-protect buffer reuse
    }

    // ---- final FC on h1(T-1) ----
    if (wid == 1 && lane < 60 && u == 0) {
        float oA = bfc[0], oB = bfc[0];
        #pragma unroll
        for (int j = 0; j < HS; ++j) {
            oA = fmaf(s_h1[g][j],     wfc[j], oA);
            oB = fmaf(s_h1[g + 3][j], wfc[j], oB);
        }
        out[bgA] = oA;
        if (okB) out[bgBr] = oB;
    }
}

extern "C" void kernel_launch(void* const* d_in, const int* in_sizes, int n_in,
                              void* d_out, int out_size, void* d_ws, size_t ws_size,
                              hipStream_t stream) {
    const float* x    = (const float*)d_in[0];
    const float* wih0 = (const float*)d_in[1];
    const float* whh0 = (const float*)d_in[2];
    const float* bih0 = (const float*)d_in[3];
    const float* bhh0 = (const float*)d_in[4];
    const float* wih1 = (const float*)d_in[5];
    const float* whh1 = (const float*)d_in[6];
    const float* bih1 = (const float*)d_in[7];
    const float* bhh1 = (const float*)d_in[8];
    const float* wfc  = (const float*)d_in[9];
    const float* bfc  = (const float*)d_in[10];
    float* out = (float*)d_out;

    dim3 grid(NBLK), block(128);
    hipLaunchKernelGGL(lstm2_fc_kernel, grid, block, 0, stream,
                       x, wih0, whh0, bih0, bhh0,
                       wih1, whh1, bih1, bhh1, wfc, bfc, out);
}

// Round 2
// 749.485 us; speedup vs baseline: 1.2135x; 1.1976x over previous
//
#include <hip/hip_runtime.h>

#define T_STEPS 512
#define HS 20       // hidden size
#define F0 10       // input features (layer 0)
#define BPB 6       // batches per block: lane-group g handles batches {g, g+3}
#define NB_TOT 4096
#define NBLK ((NB_TOT + BPB - 1) / BPB)   // 683

__device__ __forceinline__ float sigmoid_fast(float v) {
    return __fdividef(1.f, 1.f + __expf(-v));
}
__device__ __forceinline__ float tanh_fast(float v) {
    return 1.f - __fdividef(2.f, __expf(2.f * v) + 1.f);
}
#define PIN(v) asm volatile("" : "+v"(v))

// Gate-split 4-wave structure (raise wave density 1.33 -> 3 per SIMD):
//   wave0: layer0 gates {i,f} | wave1: layer0 gates {g,o} + c/h finisher
//   wave2: layer1 gates {i,f} | wave3: layer1 gates {g,o} + c/h finisher
// Each lane stores only 2 gate rows (w[2][40] = 80 floats) -> ~100 regs/wave,
// fits __launch_bounds__(256,3) budget (170) -> 12 waves/CU, 2732 waves total
// <= 3072 slots, single dispatch round. Non-finisher writes sigmoid(i),sigmoid(f)
// to LDS; finisher (sole carrier of c) reads them after a barrier, updates c,
// writes h. Two barriers/step (proven ~free in rounds 0-1). LDS h reads are
// same-address broadcasts within each 20-lane group -> no bank pressure.
__global__ __launch_bounds__(256, 3)
void lstm2_fc_kernel(const float* __restrict__ x,
                     const float* __restrict__ wih0, const float* __restrict__ whh0,
                     const float* __restrict__ bih0, const float* __restrict__ bhh0,
                     const float* __restrict__ wih1, const float* __restrict__ whh1,
                     const float* __restrict__ bih1, const float* __restrict__ bhh1,
                     const float* __restrict__ wfc,  const float* __restrict__ bfc,
                     float* __restrict__ out)
{
    const int tid   = threadIdx.x;
    const int wid   = tid >> 6;
    const int lane  = tid & 63;
    const int g     = (lane / HS) % 3;   // lanes 60..63 shadow group 0 (benign dups)
    const int u     = lane % HS;
    const int layer = wid >> 1;          // 0: waves 0,1 | 1: waves 2,3
    const int half  = wid & 1;           // 0: gates {i,f} | 1: gates {g,o} + finish
    const int q0    = 2 * half;
    const int bgA   = blockIdx.x * BPB + g;
    const int bgBr  = blockIdx.x * BPB + g + 3;
    const bool okB  = (bgBr < NB_TOT);
    const int bgB   = okB ? bgBr : (NB_TOT - 1);   // clamp reads

    __shared__ float s_h0[2][BPB][HS];  // h0 double buffer, slot = t&1 for h0(t)
    __shared__ float s_h1[2][BPB][HS];  // h1 double buffer, slot = s&1 for h1(s)
    __shared__ float ex0[BPB][HS][2];   // {sig(i), sig(f)} layer0, written by wave0
    __shared__ float ex1[BPB][HS][2];   // {sig(i), sig(f)} layer1, written by wave2

    for (int i = tid; i < 2 * BPB * HS; i += 256) {
        (&s_h0[0][0][0])[i] = 0.f;
        (&s_h1[0][0][0])[i] = 0.f;
    }

    // ---- per-lane weights: only this wave's 2 gate rows ----
    // layer0: w[qh][0..9] = wih0 row, w[qh][10..29] = whh0 row
    // layer1: w[qh][0..19] = wih1 row, w[qh][20..39] = whh1 row
    float w[2][2 * HS], bias[2];
    if (layer == 0) {
        #pragma unroll
        for (int qh = 0; qh < 2; ++qh) {
            const int row = (q0 + qh) * HS + u;
            #pragma unroll
            for (int f = 0; f < F0; ++f) { w[qh][f] = wih0[row * F0 + f]; PIN(w[qh][f]); }
            #pragma unroll
            for (int j = 0; j < HS; ++j) { w[qh][F0 + j] = whh0[row * HS + j]; PIN(w[qh][F0 + j]); }
            bias[qh] = bih0[row] + bhh0[row]; PIN(bias[qh]);
        }
    } else {
        #pragma unroll
        for (int qh = 0; qh < 2; ++qh) {
            const int row = (q0 + qh) * HS + u;
            #pragma unroll
            for (int j = 0; j < HS; ++j) { w[qh][j]      = wih1[row * HS + j]; PIN(w[qh][j]); }
            #pragma unroll
            for (int j = 0; j < HS; ++j) { w[qh][HS + j] = whh1[row * HS + j]; PIN(w[qh][HS + j]); }
            bias[qh] = bih1[row] + bhh1[row]; PIN(bias[qh]);
        }
    }

    float cA = 0.f, cB = 0.f;            // carried by finisher waves only
    const float* xbA = x + (size_t)bgA * (T_STEPS * F0);
    const float* xbB = x + (size_t)bgB * (T_STEPS * F0);

    // layer0 waves: x(t) prefetched one step ahead (both waves load; dup is cheap)
    float2 xnA[F0 / 2], xnB[F0 / 2];
    if (layer == 0) {
        const float2* pA = (const float2*)xbA;
        const float2* pB = (const float2*)xbB;
        #pragma unroll
        for (int f2 = 0; f2 < F0 / 2; ++f2) { xnA[f2] = pA[f2]; xnB[f2] = pB[f2]; }
    }

    __syncthreads();

    float tgA = 0.f, soA = 0.f, tgB = 0.f, soB = 0.f;  // finisher tanh(g), sig(o)

    #pragma unroll 1
    for (int t = 0; t <= T_STEPS; ++t) {
        // ================= phase 1: gate pre-activations =================
        if (layer == 0) {
            if (t < T_STEPS) {
                float a0A = bias[0], a1A = bias[1];
                float a0B = bias[0], a1B = bias[1];
                // x-part first (same accumulation order as verified kernel)
                #pragma unroll
                for (int f2 = 0; f2 < F0 / 2; ++f2) {
                    const int f = 2 * f2;
                    const float2 vA = xnA[f2], vB = xnB[f2];
                    a0A = fmaf(vA.x, w[0][f], a0A); a0A = fmaf(vA.y, w[0][f + 1], a0A);
                    a1A = fmaf(vA.x, w[1][f], a1A); a1A = fmaf(vA.y, w[1][f + 1], a1A);
                    a0B = fmaf(vB.x, w[0][f], a0B); a0B = fmaf(vB.y, w[0][f + 1], a0B);
                    a1B = fmaf(vB.x, w[1][f], a1B); a1B = fmaf(vB.y, w[1][f + 1], a1B);
                }
                {   // issue x(t+1) loads; latency covered by rest of iteration
                    const int tn = (t + 1 < T_STEPS) ? (t + 1) : (T_STEPS - 1);
                    const float2* pA = (const float2*)(xbA + tn * F0);
                    const float2* pB = (const float2*)(xbB + tn * F0);
                    #pragma unroll
                    for (int f2 = 0; f2 < F0 / 2; ++f2) { xnA[f2] = pA[f2]; xnB[f2] = pB[f2]; }
                }
                // h0(t-1) part, slot (t-1)&1 == (t+1)&1
                const float* hpA = &s_h0[(t + 1) & 1][g][0];
                const float* hpB = &s_h0[(t + 1) & 1][g + 3][0];
                #pragma unroll
                for (int q4 = 0; q4 < HS / 4; ++q4) {
                    const float4 hA = *(const float4*)(hpA + 4 * q4);
                    const float4 hB = *(const float4*)(hpB + 4 * q4);
                    const float eA[4] = {hA.x, hA.y, hA.z, hA.w};
                    const float eB[4] = {hB.x, hB.y, hB.z, hB.w};
                    #pragma unroll
                    for (int e = 0; e < 4; ++e) {
                        const int k = F0 + 4 * q4 + e;
                        a0A = fmaf(eA[e], w[0][k], a0A);  a0B = fmaf(eB[e], w[0][k], a0B);
                        a1A = fmaf(eA[e], w[1][k], a1A);  a1B = fmaf(eB[e], w[1][k], a1B);
                    }
                }
                if (half == 0) {
                    *(float2*)&ex0[g][u][0]     = make_float2(sigmoid_fast(a0A), sigmoid_fast(a1A));
                    *(float2*)&ex0[g + 3][u][0] = make_float2(sigmoid_fast(a0B), sigmoid_fast(a1B));
                } else {
                    tgA = tanh_fast(a0A); soA = sigmoid_fast(a1A);
                    tgB = tanh_fast(a0B); soB = sigmoid_fast(a1B);
                }
            }
        } else {
            if (t >= 1) {
                // layer1 computes step s = t-1
                float a0A = bias[0], a1A = bias[1];
                float a0B = bias[0], a1B = bias[1];
                // h0(s) part, slot (t-1)&1
                const float* hpA = &s_h0[(t - 1) & 1][g][0];
                const float* hpB = &s_h0[(t - 1) & 1][g + 3][0];
                #pragma unroll
                for (int q4 = 0; q4 < HS / 4; ++q4) {
                    const float4 hA = *(const float4*)(hpA + 4 * q4);
                    const float4 hB = *(const float4*)(hpB + 4 * q4);
                    const float eA[4] = {hA.x, hA.y, hA.z, hA.w};
                    const float eB[4] = {hB.x, hB.y, hB.z, hB.w};
                    #pragma unroll
                    for (int e = 0; e < 4; ++e) {
                        const int k = 4 * q4 + e;
                        a0A = fmaf(eA[e], w[0][k], a0A);  a0B = fmaf(eB[e], w[0][k], a0B);
                        a1A = fmaf(eA[e], w[1][k], a1A);  a1B = fmaf(eB[e], w[1][k], a1B);
                    }
                }
                // h1(s-1) part, slot (s-1)&1 == t&1
                const float* ppA = &s_h1[t & 1][g][0];
                const float* ppB = &s_h1[t & 1][g + 3][0];
                #pragma unroll
                for (int q4 = 0; q4 < HS / 4; ++q4) {
                    const float4 hA = *(const float4*)(ppA + 4 * q4);
                    const float4 hB = *(const float4*)(ppB + 4 * q4);
                    const float eA[4] = {hA.x, hA.y, hA.z, hA.w};
                    const float eB[4] = {hB.x, hB.y, hB.z, hB.w};
                    #pragma unroll
                    for (int e = 0; e < 4; ++e) {
                        const int k = HS + 4 * q4 + e;
                        a0A = fmaf(eA[e], w[0][k], a0A);  a0B = fmaf(eB[e], w[0][k], a0B);
                        a1A = fmaf(eA[e], w[1][k], a1A);  a1B = fmaf(eB[e], w[1][k], a1B);
                    }
                }
                if (half == 0) {
                    *(float2*)&ex1[g][u][0]     = make_float2(sigmoid_fast(a0A), sigmoid_fast(a1A));
                    *(float2*)&ex1[g + 3][u][0] = make_float2(sigmoid_fast(a0B), sigmoid_fast(a1B));
                } else {
                    tgA = tanh_fast(a0A); soA = sigmoid_fast(a1A);
                    tgB = tanh_fast(a0B); soB = sigmoid_fast(a1B);
                }
            }
        }
        __syncthreads();   // publish sig(i),sig(f) halves

        // ================= phase 2: finishers update c, write h =================
        if (half == 1) {
            const bool act = (layer == 0) ? (t < T_STEPS) : (t >= 1);
            if (act) {
                float2 sifA, sifB;
                if (layer == 0) {
                    sifA = *(const float2*)&ex0[g][u][0];
                    sifB = *(const float2*)&ex0[g + 3][u][0];
                } else {
                    sifA = *(const float2*)&ex1[g][u][0];
                    sifB = *(const float2*)&ex1[g + 3][u][0];
                }
                cA = fmaf(sifA.y, cA, sifA.x * tgA);   // c = sig(f)*c + sig(i)*tanh(g)
                cB = fmaf(sifB.y, cB, sifB.x * tgB);
                const float hA = soA * tanh_fast(cA);
                const float hB = soB * tanh_fast(cB);
                if (layer == 0) {
                    s_h0[t & 1][g][u]       = hA;
                    s_h0[t & 1][g + 3][u]   = hB;
                } else {
                    s_h1[(t - 1) & 1][g][u]     = hA;
                    s_h1[(t - 1) & 1][g + 3][u] = hB;
                }
            }
        }
        __syncthreads();   // publish h; WAR-protect ex* and h buffers
    }

    // ---- final FC on h1(T-1), slot (T-1)&1 ----
    if (wid == 3 && lane < 60 && u == 0) {
        const int sl = (T_STEPS - 1) & 1;
        float oA = bfc[0], oB = bfc[0];
        #pragma unroll
        for (int j = 0; j < HS; ++j) {
            oA = fmaf(s_h1[sl][g][j],     wfc[j], oA);
            oB = fmaf(s_h1[sl][g + 3][j], wfc[j], oB);
        }
        out[bgA] = oA;
        if (okB) out[bgBr] = oB;
    }
}

extern "C" void kernel_launch(void* const* d_in, const int* in_sizes, int n_in,
                              void* d_out, int out_size, void* d_ws, size_t ws_size,
                              hipStream_t stream) {
    const float* x    = (const float*)d_in[0];
    const float* wih0 = (const float*)d_in[1];
    const float* whh0 = (const float*)d_in[2];
    const float* bih0 = (const float*)d_in[3];
    const float* bhh0 = (const float*)d_in[4];
    const float* wih1 = (const float*)d_in[5];
    const float* whh1 = (const float*)d_in[6];
    const float* bih1 = (const float*)d_in[7];
    const float* bhh1 = (const float*)d_in[8];
    const float* wfc  = (const float*)d_in[9];
    const float* bfc  = (const float*)d_in[10];
    float* out = (float*)d_out;

    dim3 grid(NBLK), block(256);
    hipLaunchKernelGGL(lstm2_fc_kernel, grid, block, 0, stream,
                       x, wih0, whh0, bih0, bhh0,
                       wih1, whh1, bih1, bhh1, wfc, bfc, out);
}